// Round 1
// baseline (769.002 us; speedup 1.0000x reference)
//
#include <hip/hip_runtime.h>
#include <cstdint>

#define FEAT 4096
#define DIN  64
#define HS   32
#define NL   8
#define TT   300
#define BB   64
#define G4   128   // 4*HS

__device__ __forceinline__ float sigm(float x){ return __fdividef(1.f, 1.f + __expf(-x)); }
__device__ __forceinline__ float tanh_f(float x){ return __fdividef(2.f, 1.f + __expf(-2.f*x)) - 1.f; }

// ---------------------------------------------------------------------------
// Kernel 1: per 64-row tile of the (B*T, .) matrix:
//   h1 = relu(x @ W0^T + b0)          [64 x 64], K=4096 (LDS-staged)
//   h2 = h1 @ W1^T + b1               [64 x 64]
//   gx0 = h2 @ Wih0^T + (bih0+bhh0)   [64 x 128]  -> global ws
// ---------------------------------------------------------------------------
__global__ __launch_bounds__(256) void fc_front(
    const float* __restrict__ x,
    const float* __restrict__ W0, const float* __restrict__ b0,
    const float* __restrict__ W1, const float* __restrict__ b1,
    const float* __restrict__ Wih0,
    const float* __restrict__ bih, const float* __restrict__ bhh,
    float* __restrict__ gx0)
{
    __shared__ __align__(16) float xs[32][64];   // transposed: xs[k][row]
    __shared__ __align__(16) float wsm[32][64];  // transposed: wsm[k][col]
    __shared__ __align__(16) float h1s[64][68];
    __shared__ __align__(16) float h2s[64][68];

    const int tid  = threadIdx.x;
    const int tc   = tid & 15;    // col group (4 cols)
    const int tr   = tid >> 4;    // row group (4 rows)
    const int r0   = blockIdx.x * 64;
    const int srow = tid >> 2;            // staging row / W0 row
    const int sk   = (tid & 3) * 8;       // staging k offset

    float acc[4][4] = {};

    for (int kb = 0; kb < FEAT; kb += 32) {
        // issue global loads before the barrier so they overlap it
        float4 a0 = *(const float4*)(x  + (size_t)(r0 + srow) * FEAT + kb + sk);
        float4 a1 = *(const float4*)(x  + (size_t)(r0 + srow) * FEAT + kb + sk + 4);
        float4 w0 = *(const float4*)(W0 + (size_t)srow        * FEAT + kb + sk);
        float4 w1 = *(const float4*)(W0 + (size_t)srow        * FEAT + kb + sk + 4);
        __syncthreads();   // previous iter's reads done
        xs [sk+0][srow] = a0.x; xs [sk+1][srow] = a0.y; xs [sk+2][srow] = a0.z; xs [sk+3][srow] = a0.w;
        xs [sk+4][srow] = a1.x; xs [sk+5][srow] = a1.y; xs [sk+6][srow] = a1.z; xs [sk+7][srow] = a1.w;
        wsm[sk+0][srow] = w0.x; wsm[sk+1][srow] = w0.y; wsm[sk+2][srow] = w0.z; wsm[sk+3][srow] = w0.w;
        wsm[sk+4][srow] = w1.x; wsm[sk+5][srow] = w1.y; wsm[sk+6][srow] = w1.z; wsm[sk+7][srow] = w1.w;
        __syncthreads();
        #pragma unroll
        for (int k = 0; k < 32; ++k) {
            float4 av = *(const float4*)&xs [k][tr * 4];
            float4 bv = *(const float4*)&wsm[k][tc * 4];
            float a_[4] = {av.x, av.y, av.z, av.w};
            float b_[4] = {bv.x, bv.y, bv.z, bv.w};
            #pragma unroll
            for (int i = 0; i < 4; ++i)
                #pragma unroll
                for (int j = 0; j < 4; ++j)
                    acc[i][j] = fmaf(a_[i], b_[j], acc[i][j]);
        }
    }

    // epilogue 1: bias + relu -> h1s
    __syncthreads();
    #pragma unroll
    for (int i = 0; i < 4; ++i)
        #pragma unroll
        for (int j = 0; j < 4; ++j)
            h1s[tr*4 + i][tc*4 + j] = fmaxf(acc[i][j] + b0[tc*4 + j], 0.f);
    __syncthreads();

    // phase 2: h2 = h1 @ W1^T + b1   (W1 from L2)
    float acc2[4][4] = {};
    #pragma unroll
    for (int k4 = 0; k4 < 16; ++k4) {
        const int k = k4 * 4;
        float4 a[4], w[4];
        #pragma unroll
        for (int i = 0; i < 4; ++i) a[i] = *(const float4*)&h1s[tr*4 + i][k];
        #pragma unroll
        for (int j = 0; j < 4; ++j) w[j] = *(const float4*)(W1 + (size_t)(tc*4 + j) * DIN + k);
        #pragma unroll
        for (int i = 0; i < 4; ++i)
            #pragma unroll
            for (int j = 0; j < 4; ++j)
                acc2[i][j] += a[i].x*w[j].x + a[i].y*w[j].y + a[i].z*w[j].z + a[i].w*w[j].w;
    }
    __syncthreads();
    #pragma unroll
    for (int i = 0; i < 4; ++i)
        #pragma unroll
        for (int j = 0; j < 4; ++j)
            h2s[tr*4 + i][tc*4 + j] = acc2[i][j] + b1[tc*4 + j];
    __syncthreads();

    // phase 3: gx0 = h2 @ Wih0^T + (bih0 + bhh0), 128 gate cols in 2 passes
    #pragma unroll
    for (int p = 0; p < 2; ++p) {
        float acc3[4][4] = {};
        #pragma unroll
        for (int k4 = 0; k4 < 16; ++k4) {
            const int k = k4 * 4;
            float4 a[4], w[4];
            #pragma unroll
            for (int i = 0; i < 4; ++i) a[i] = *(const float4*)&h2s[tr*4 + i][k];
            #pragma unroll
            for (int j = 0; j < 4; ++j) w[j] = *(const float4*)(Wih0 + (size_t)(p*64 + tc*4 + j) * DIN + k);
            #pragma unroll
            for (int i = 0; i < 4; ++i)
                #pragma unroll
                for (int j = 0; j < 4; ++j)
                    acc3[i][j] += a[i].x*w[j].x + a[i].y*w[j].y + a[i].z*w[j].z + a[i].w*w[j].w;
        }
        const int g0 = p * 64 + tc * 4;
        #pragma unroll
        for (int i = 0; i < 4; ++i) {
            float4 ov;
            ov.x = acc3[i][0] + bih[g0+0] + bhh[g0+0];
            ov.y = acc3[i][1] + bih[g0+1] + bhh[g0+1];
            ov.z = acc3[i][2] + bih[g0+2] + bhh[g0+2];
            ov.w = acc3[i][3] + bih[g0+3] + bhh[g0+3];
            *(float4*)(gx0 + (size_t)(r0 + tr*4 + i) * G4 + g0) = ov;
        }
    }
}

// ---------------------------------------------------------------------------
// Kernel 2: wavefront-pipelined 8-layer LSTM + fused fc1/fc2 epilogue.
// One block per batch element; wave l = layer l; t = superstep - l.
// Gate weights in VGPRs; h exchanged via 2-slot LDS rings; gx0 prefetched.
// ---------------------------------------------------------------------------
__global__ __launch_bounds__(512, 2) void lstm_all(
    const float* __restrict__ gx0,   // [B*T][128], biases of layer 0 folded in
    const float* __restrict__ Wih,   // [7][128][32]
    const float* __restrict__ Whh,   // [8][128][32]
    const float* __restrict__ bih,   // [8][128]
    const float* __restrict__ bhh,   // [8][128]
    const float* __restrict__ Wfc1, const float* __restrict__ bfc1,
    const float* __restrict__ Wfc2, const float* __restrict__ bfc2,
    float* __restrict__ out)         // [B]
{
    const int b    = blockIdx.x;
    const int tid  = threadIdx.x;
    const int l    = tid >> 6;     // wave id = layer
    const int lane = tid & 63;
    const int q0   = lane;         // gate rows owned by this lane
    const int q1   = lane + 64;

    __shared__ __align__(16) float hbuf[NL][2][HS];  // h_l[t] parity ring
    __shared__ __align__(16) float gbuf[NL][G4];     // per-wave gate exchange
    __shared__ __align__(16) float h7[TT][HS];       // layer-7 output sequence
    __shared__ float red[NL];

    // ---- load this lane's gate weight rows into registers ----
    float whh0[HS], whh1[HS], wih0[HS], wih1[HS];
    {
        const float* whhl = Whh + (size_t)l * G4 * HS;
        const float* wihl = Wih + (size_t)(l > 0 ? l - 1 : 0) * G4 * HS;
        #pragma unroll
        for (int k4 = 0; k4 < 8; ++k4) {
            float4 v0 = *(const float4*)(whhl + q0 * HS + 4 * k4);
            float4 v1 = *(const float4*)(whhl + q1 * HS + 4 * k4);
            whh0[4*k4+0]=v0.x; whh0[4*k4+1]=v0.y; whh0[4*k4+2]=v0.z; whh0[4*k4+3]=v0.w;
            whh1[4*k4+0]=v1.x; whh1[4*k4+1]=v1.y; whh1[4*k4+2]=v1.z; whh1[4*k4+3]=v1.w;
            float4 u0 = *(const float4*)(wihl + q0 * HS + 4 * k4);
            float4 u1 = *(const float4*)(wihl + q1 * HS + 4 * k4);
            wih0[4*k4+0]=u0.x; wih0[4*k4+1]=u0.y; wih0[4*k4+2]=u0.z; wih0[4*k4+3]=u0.w;
            wih1[4*k4+0]=u1.x; wih1[4*k4+1]=u1.y; wih1[4*k4+2]=u1.z; wih1[4*k4+3]=u1.w;
        }
    }
    const float bias0 = (l > 0) ? (bih[l*G4 + q0] + bhh[l*G4 + q0]) : 0.f;
    const float bias1 = (l > 0) ? (bih[l*G4 + q1] + bhh[l*G4 + q1]) : 0.f;

    float c_state = 0.f;           // lanes 0..31: cell state for h-index = lane

    const float* gxb = gx0 + (size_t)b * TT * G4;
    float pf0 = 0.f, pf1 = 0.f;
    if (l == 0) { pf0 = gxb[q0]; pf1 = gxb[q1]; }   // prefetch t=0

    for (int s = 0; s < TT + NL - 1; ++s) {
        const int t = s - l;
        if (0 <= t && t < TT) {
            float acc0, acc1;
            if (l == 0) {
                acc0 = pf0; acc1 = pf1;
                const int tn = t + 1;
                if (tn < TT) { pf0 = gxb[(size_t)tn * G4 + q0]; pf1 = gxb[(size_t)tn * G4 + q1]; }
            } else {
                acc0 = bias0; acc1 = bias1;
            }
            float a0a = 0.f, a0b = 0.f, a1a = 0.f, a1b = 0.f;
            if (t > 0) {   // recurrent term
                const float4* hp = (const float4*)hbuf[l][(t - 1) & 1];
                #pragma unroll
                for (int k4 = 0; k4 < 8; ++k4) {
                    float4 v = hp[k4];
                    a0a = fmaf(whh0[4*k4+0], v.x, a0a); a0b = fmaf(whh0[4*k4+1], v.y, a0b);
                    a0a = fmaf(whh0[4*k4+2], v.z, a0a); a0b = fmaf(whh0[4*k4+3], v.w, a0b);
                    a1a = fmaf(whh1[4*k4+0], v.x, a1a); a1b = fmaf(whh1[4*k4+1], v.y, a1b);
                    a1a = fmaf(whh1[4*k4+2], v.z, a1a); a1b = fmaf(whh1[4*k4+3], v.w, a1b);
                }
            }
            if (l > 0) {   // input term from layer l-1
                const float4* hq = (const float4*)hbuf[l - 1][t & 1];
                #pragma unroll
                for (int k4 = 0; k4 < 8; ++k4) {
                    float4 v = hq[k4];
                    a0a = fmaf(wih0[4*k4+0], v.x, a0a); a0b = fmaf(wih0[4*k4+1], v.y, a0b);
                    a0a = fmaf(wih0[4*k4+2], v.z, a0a); a0b = fmaf(wih0[4*k4+3], v.w, a0b);
                    a1a = fmaf(wih1[4*k4+0], v.x, a1a); a1b = fmaf(wih1[4*k4+1], v.y, a1b);
                    a1a = fmaf(wih1[4*k4+2], v.z, a1a); a1b = fmaf(wih1[4*k4+3], v.w, a1b);
                }
            }
            acc0 += a0a + a0b;
            acc1 += a1a + a1b;
            gbuf[l][q0] = acc0;
            gbuf[l][q1] = acc1;
            asm volatile("s_waitcnt lgkmcnt(0)" ::: "memory");  // in-wave LDS visibility
            if (lane < HS) {
                const float ig = gbuf[l][lane];
                const float fg = gbuf[l][HS + lane];
                const float gg = gbuf[l][2*HS + lane];
                const float og = gbuf[l][3*HS + lane];
                c_state = sigm(fg) * c_state + sigm(ig) * tanh_f(gg);
                const float hv = sigm(og) * tanh_f(c_state);
                hbuf[l][t & 1][lane] = hv;
                if (l == NL - 1) h7[t][lane] = hv;
            }
        }
        __syncthreads();
    }

    // ---- fused fc1 (over H) + fc2 (over T) ----
    float part = 0.f;
    for (int t = tid; t < TT; t += 512) {
        float st = 0.f;
        #pragma unroll
        for (int j = 0; j < HS; ++j) st = fmaf(h7[t][j], Wfc1[j], st);
        part += (st + bfc1[0]) * Wfc2[t];
    }
    #pragma unroll
    for (int off = 32; off >= 1; off >>= 1) part += __shfl_down(part, off, 64);
    if (lane == 0) red[l] = part;
    __syncthreads();
    if (tid == 0) {
        float tot = 0.f;
        #pragma unroll
        for (int w = 0; w < NL; ++w) tot += red[w];
        out[b] = tot + bfc2[0];
    }
}

// ---------------------------------------------------------------------------
extern "C" void kernel_launch(void* const* d_in, const int* in_sizes, int n_in,
                              void* d_out, int out_size, void* d_ws, size_t ws_size,
                              hipStream_t stream) {
    const float* x    = (const float*)d_in[0];
    const float* W0   = (const float*)d_in[1];
    const float* b0   = (const float*)d_in[2];
    const float* W1   = (const float*)d_in[3];
    const float* b1   = (const float*)d_in[4];
    const float* Wih0 = (const float*)d_in[5];
    const float* Wih  = (const float*)d_in[6];
    const float* Whh  = (const float*)d_in[7];
    const float* bih  = (const float*)d_in[8];
    const float* bhh  = (const float*)d_in[9];
    const float* Wfc1 = (const float*)d_in[10];
    const float* bfc1 = (const float*)d_in[11];
    const float* Wfc2 = (const float*)d_in[12];
    const float* bfc2 = (const float*)d_in[13];

    float* gx0 = (float*)d_ws;   // [B*T][128] = 9.83 MB

    fc_front<<<(BB * TT) / 64, 256, 0, stream>>>(x, W0, b0, W1, b1, Wih0, bih, bhh, gx0);
    lstm_all<<<BB, 512, 0, stream>>>(gx0, Wih, Whh, bih, bhh, Wfc1, bfc1, Wfc2, bfc2,
                                     (float*)d_out);
}

// Round 2
// 432.342 us; speedup vs baseline: 1.7787x; 1.7787x over previous
//
#include <hip/hip_runtime.h>
#include <cstdint>

#define FEAT 4096
#define DIN  64
#define HS   32
#define NL   8
#define TT   300
#define BB   64
#define G4   128           // 4*HS
#define MROWS (BB*TT)      // 19200
#define KS    4            // K-split for big GEMM
#define KSLICE (FEAT/KS)   // 1024
#define BK    64
#define NCHUNK (KSLICE/BK) // 16

typedef __bf16 bf16x8 __attribute__((ext_vector_type(8)));
typedef float  f32x4  __attribute__((ext_vector_type(4)));
typedef unsigned short u16x8 __attribute__((ext_vector_type(8)));

__device__ __forceinline__ float sigm(float x){ return __fdividef(1.f, 1.f + __expf(-x)); }
__device__ __forceinline__ float tanh_f(float x){ return __fdividef(2.f, 1.f + __expf(-2.f*x)) - 1.f; }

__device__ __forceinline__ unsigned short bf16_rne(float f){
    uint32_t u = __float_as_uint(f);
    return (unsigned short)((u + 0x7FFFu + ((u >> 16) & 1u)) >> 16);
}

// ---------------------------------------------------------------------------
// Prep: split W0 [64][4096] fp32 into bf16 hi/lo planes (RNE + residual).
// ---------------------------------------------------------------------------
__global__ __launch_bounds__(256) void w0split(const float* __restrict__ W0,
                                               unsigned short* __restrict__ wh,
                                               unsigned short* __restrict__ wl)
{
    const int i = (blockIdx.x * 256 + threadIdx.x) * 4;
    float4 v = *(const float4*)(W0 + i);
    float f[4] = {v.x, v.y, v.z, v.w};
    unsigned short hh[4], ll[4];
    #pragma unroll
    for (int j = 0; j < 4; ++j) {
        unsigned short h = bf16_rne(f[j]);
        float fh = __uint_as_float((uint32_t)h << 16);
        hh[j] = h;
        ll[j] = bf16_rne(f[j] - fh);
    }
    *(ushort4*)(wh + i) = make_ushort4(hh[0], hh[1], hh[2], hh[3]);
    *(ushort4*)(wl + i) = make_ushort4(ll[0], ll[1], ll[2], ll[3]);
}

// ---------------------------------------------------------------------------
// Kernel 1: h1pre partials = x @ W0^T, bf16x3-split MFMA, split-K.
// grid (300, KS); block 256 (4 waves as 2x2 over a 64x64 output tile).
// Double-buffered LDS, XOR-swizzled granules, raw barrier (no vmcnt drain).
// ---------------------------------------------------------------------------
__global__ __launch_bounds__(256, 2) void fc_gemm1(
    const float* __restrict__ x,
    const unsigned short* __restrict__ wh,
    const unsigned short* __restrict__ wl,
    float* __restrict__ part)
{
    __shared__ __align__(16) unsigned short xh[2][64][64];
    __shared__ __align__(16) unsigned short xl[2][64][64];
    __shared__ __align__(16) unsigned short wh_s[2][64][64];
    __shared__ __align__(16) unsigned short wl_s[2][64][64];

    const int t   = threadIdx.x;
    const int l   = t & 63;
    const int w   = t >> 6;
    const int rbb = (w >> 1) * 32;     // wave row block
    const int cbb = (w & 1) * 32;      // wave col block
    const int r0  = blockIdx.x * 64;
    const int kb0 = blockIdx.y * KSLICE;

    const int srow = t >> 3;           // staging row 0..31 (j adds +32)
    const int sg   = t & 7;            // staging granule (8 bf16 = 16B)

    f32x4 acc[2][2];
    #pragma unroll
    for (int i = 0; i < 2; ++i)
        #pragma unroll
        for (int j = 0; j < 2; ++j)
            acc[i][j] = (f32x4){0.f, 0.f, 0.f, 0.f};

    float4 xr[2][2];
    uint4  w0h[2], w0l[2];

    auto LOAD = [&](int c) {
        const float* xb = x + (size_t)r0 * FEAT + kb0 + c * BK;
        xr[0][0] = *(const float4*)(xb + (size_t)srow * FEAT + sg * 8);
        xr[0][1] = *(const float4*)(xb + (size_t)srow * FEAT + sg * 8 + 4);
        xr[1][0] = *(const float4*)(xb + (size_t)(srow + 32) * FEAT + sg * 8);
        xr[1][1] = *(const float4*)(xb + (size_t)(srow + 32) * FEAT + sg * 8 + 4);
        const int wo = kb0 + c * BK + sg * 8;
        w0h[0] = *(const uint4*)(wh + (size_t)srow * FEAT + wo);
        w0h[1] = *(const uint4*)(wh + (size_t)(srow + 32) * FEAT + wo);
        w0l[0] = *(const uint4*)(wl + (size_t)srow * FEAT + wo);
        w0l[1] = *(const uint4*)(wl + (size_t)(srow + 32) * FEAT + wo);
    };

    auto STORE = [&](int c) {
        const int buf = c & 1;
        #pragma unroll
        for (int j = 0; j < 2; ++j) {
            const int row = srow + j * 32;
            const int gsw = (sg ^ (row & 7)) * 8;
            float f0[8] = {xr[j][0].x, xr[j][0].y, xr[j][0].z, xr[j][0].w,
                           xr[j][1].x, xr[j][1].y, xr[j][1].z, xr[j][1].w};
            u16x8 vh, vl;
            #pragma unroll
            for (int i = 0; i < 8; ++i) {
                uint32_t u  = __float_as_uint(f0[i]);
                uint32_t rh = (u + 0x7FFFu + ((u >> 16) & 1u)) >> 16;
                vh[i] = (unsigned short)rh;
                float fl = f0[i] - __uint_as_float(rh << 16);
                uint32_t u2 = __float_as_uint(fl);
                vl[i] = (unsigned short)((u2 + 0x7FFFu + ((u2 >> 16) & 1u)) >> 16);
            }
            *(u16x8*)&xh[buf][row][gsw] = vh;
            *(u16x8*)&xl[buf][row][gsw] = vl;
            *(uint4*)&wh_s[buf][row][gsw] = w0h[j];
            *(uint4*)&wl_s[buf][row][gsw] = w0l[j];
        }
    };

    auto COMPUTE = [&](int buf) {
        #pragma unroll
        for (int kstep = 0; kstep < 2; ++kstep) {
            const int gA = kstep * 4 + (l >> 4);
            bf16x8 Ah[2], Al[2], Bh[2], Bl[2];
            #pragma unroll
            for (int rf = 0; rf < 2; ++rf) {
                const int ra  = rbb + rf * 16 + (l & 15);
                const int off = (gA ^ (ra & 7)) * 8;
                Ah[rf] = __builtin_bit_cast(bf16x8, *(const u16x8*)&xh[buf][ra][off]);
                Al[rf] = __builtin_bit_cast(bf16x8, *(const u16x8*)&xl[buf][ra][off]);
            }
            #pragma unroll
            for (int cf = 0; cf < 2; ++cf) {
                const int cb  = cbb + cf * 16 + (l & 15);
                const int off = (gA ^ (cb & 7)) * 8;
                Bh[cf] = __builtin_bit_cast(bf16x8, *(const u16x8*)&wh_s[buf][cb][off]);
                Bl[cf] = __builtin_bit_cast(bf16x8, *(const u16x8*)&wl_s[buf][cb][off]);
            }
            #pragma unroll
            for (int rf = 0; rf < 2; ++rf)
                #pragma unroll
                for (int cf = 0; cf < 2; ++cf) {
                    acc[rf][cf] = __builtin_amdgcn_mfma_f32_16x16x32_bf16(Ah[rf], Bh[cf], acc[rf][cf], 0, 0, 0);
                    acc[rf][cf] = __builtin_amdgcn_mfma_f32_16x16x32_bf16(Al[rf], Bh[cf], acc[rf][cf], 0, 0, 0);
                    acc[rf][cf] = __builtin_amdgcn_mfma_f32_16x16x32_bf16(Ah[rf], Bl[cf], acc[rf][cf], 0, 0, 0);
                }
        }
    };

    LOAD(0);
    for (int c = 0; c < NCHUNK; ++c) {
        STORE(c);                       // compiler inserts vmcnt wait for regs
        if (c + 1 < NCHUNK) LOAD(c + 1);// next chunk stays in flight across barrier
        asm volatile("s_waitcnt lgkmcnt(0)" ::: "memory");
        __builtin_amdgcn_s_barrier();
        COMPUTE(c & 1);
    }

    // store fp32 partials: part[ks][row][col]
    #pragma unroll
    for (int rf = 0; rf < 2; ++rf)
        #pragma unroll
        for (int cf = 0; cf < 2; ++cf)
            #pragma unroll
            for (int r = 0; r < 4; ++r) {
                const int row = r0 + rbb + rf * 16 + (l >> 4) * 4 + r;
                const int col = cbb + cf * 16 + (l & 15);
                part[((size_t)blockIdx.y * MROWS + row) * 64 + col] = acc[rf][cf][r];
            }
}

// ---------------------------------------------------------------------------
// Kernel 2: reduce partials -> relu(h1) -> h2 = h1@W1^T+b1 -> gx0 = h2@Wih0^T+biases
// ---------------------------------------------------------------------------
__global__ __launch_bounds__(256) void fc_tail(
    const float* __restrict__ part, const float* __restrict__ b0,
    const float* __restrict__ W1, const float* __restrict__ b1,
    const float* __restrict__ Wih0,
    const float* __restrict__ bih, const float* __restrict__ bhh,
    float* __restrict__ gx0)
{
    __shared__ __align__(16) float h1s[64][68];
    __shared__ __align__(16) float h2s[64][68];

    const int tid = threadIdx.x;
    const int tc  = tid & 15;
    const int tr  = tid >> 4;
    const int r0  = blockIdx.x * 64;

    // reduce KS partials + bias + relu -> h1s
    {
        const int row = tid >> 2;
        const int c0  = (tid & 3) * 16;
        float4 s[4];
        #pragma unroll
        for (int i = 0; i < 4; ++i)
            s[i] = *(const float4*)(part + ((size_t)(r0 + row)) * 64 + c0 + 4 * i);
        #pragma unroll
        for (int ks = 1; ks < KS; ++ks)
            #pragma unroll
            for (int i = 0; i < 4; ++i) {
                float4 v = *(const float4*)(part + ((size_t)ks * MROWS + r0 + row) * 64 + c0 + 4 * i);
                s[i].x += v.x; s[i].y += v.y; s[i].z += v.z; s[i].w += v.w;
            }
        #pragma unroll
        for (int i = 0; i < 4; ++i) {
            float4 bv = *(const float4*)(b0 + c0 + 4 * i);
            float4 o;
            o.x = fmaxf(s[i].x + bv.x, 0.f);
            o.y = fmaxf(s[i].y + bv.y, 0.f);
            o.z = fmaxf(s[i].z + bv.z, 0.f);
            o.w = fmaxf(s[i].w + bv.w, 0.f);
            *(float4*)&h1s[row][c0 + 4 * i] = o;
        }
    }
    __syncthreads();

    // h2 = h1 @ W1^T + b1
    float acc2[4][4] = {};
    #pragma unroll
    for (int k4 = 0; k4 < 16; ++k4) {
        const int k = k4 * 4;
        float4 a[4], wv[4];
        #pragma unroll
        for (int i = 0; i < 4; ++i) a[i] = *(const float4*)&h1s[tr * 4 + i][k];
        #pragma unroll
        for (int j = 0; j < 4; ++j) wv[j] = *(const float4*)(W1 + (size_t)(tc * 4 + j) * DIN + k);
        #pragma unroll
        for (int i = 0; i < 4; ++i)
            #pragma unroll
            for (int j = 0; j < 4; ++j)
                acc2[i][j] += a[i].x * wv[j].x + a[i].y * wv[j].y + a[i].z * wv[j].z + a[i].w * wv[j].w;
    }
    __syncthreads();
    #pragma unroll
    for (int i = 0; i < 4; ++i)
        #pragma unroll
        for (int j = 0; j < 4; ++j)
            h2s[tr * 4 + i][tc * 4 + j] = acc2[i][j] + b1[tc * 4 + j];
    __syncthreads();

    // gx0 = h2 @ Wih0^T + (bih0 + bhh0)
    #pragma unroll
    for (int p = 0; p < 2; ++p) {
        float acc3[4][4] = {};
        #pragma unroll
        for (int k4 = 0; k4 < 16; ++k4) {
            const int k = k4 * 4;
            float4 a[4], wv[4];
            #pragma unroll
            for (int i = 0; i < 4; ++i) a[i] = *(const float4*)&h2s[tr * 4 + i][k];
            #pragma unroll
            for (int j = 0; j < 4; ++j) wv[j] = *(const float4*)(Wih0 + (size_t)(p * 64 + tc * 4 + j) * DIN + k);
            #pragma unroll
            for (int i = 0; i < 4; ++i)
                #pragma unroll
                for (int j = 0; j < 4; ++j)
                    acc3[i][j] += a[i].x * wv[j].x + a[i].y * wv[j].y + a[i].z * wv[j].z + a[i].w * wv[j].w;
        }
        const int g0 = p * 64 + tc * 4;
        #pragma unroll
        for (int i = 0; i < 4; ++i) {
            float4 ov;
            ov.x = acc3[i][0] + bih[g0 + 0] + bhh[g0 + 0];
            ov.y = acc3[i][1] + bih[g0 + 1] + bhh[g0 + 1];
            ov.z = acc3[i][2] + bih[g0 + 2] + bhh[g0 + 2];
            ov.w = acc3[i][3] + bih[g0 + 3] + bhh[g0 + 3];
            *(float4*)(gx0 + (size_t)(r0 + tr * 4 + i) * G4 + g0) = ov;
        }
    }
}

// ---------------------------------------------------------------------------
// Kernel 3: wavefront-pipelined 8-layer LSTM + fused fc1/fc2 (unchanged).
// ---------------------------------------------------------------------------
__global__ __launch_bounds__(512, 2) void lstm_all(
    const float* __restrict__ gx0,
    const float* __restrict__ Wih, const float* __restrict__ Whh,
    const float* __restrict__ bih, const float* __restrict__ bhh,
    const float* __restrict__ Wfc1, const float* __restrict__ bfc1,
    const float* __restrict__ Wfc2, const float* __restrict__ bfc2,
    float* __restrict__ out)
{
    const int b    = blockIdx.x;
    const int tid  = threadIdx.x;
    const int l    = tid >> 6;
    const int lane = tid & 63;
    const int q0   = lane;
    const int q1   = lane + 64;

    __shared__ __align__(16) float hbuf[NL][2][HS];
    __shared__ __align__(16) float gbuf[NL][G4];
    __shared__ __align__(16) float h7[TT][HS];
    __shared__ float red[NL];

    float whh0[HS], whh1[HS], wih0[HS], wih1[HS];
    {
        const float* whhl = Whh + (size_t)l * G4 * HS;
        const float* wihl = Wih + (size_t)(l > 0 ? l - 1 : 0) * G4 * HS;
        #pragma unroll
        for (int k4 = 0; k4 < 8; ++k4) {
            float4 v0 = *(const float4*)(whhl + q0 * HS + 4 * k4);
            float4 v1 = *(const float4*)(whhl + q1 * HS + 4 * k4);
            whh0[4*k4+0]=v0.x; whh0[4*k4+1]=v0.y; whh0[4*k4+2]=v0.z; whh0[4*k4+3]=v0.w;
            whh1[4*k4+0]=v1.x; whh1[4*k4+1]=v1.y; whh1[4*k4+2]=v1.z; whh1[4*k4+3]=v1.w;
            float4 u0 = *(const float4*)(wihl + q0 * HS + 4 * k4);
            float4 u1 = *(const float4*)(wihl + q1 * HS + 4 * k4);
            wih0[4*k4+0]=u0.x; wih0[4*k4+1]=u0.y; wih0[4*k4+2]=u0.z; wih0[4*k4+3]=u0.w;
            wih1[4*k4+0]=u1.x; wih1[4*k4+1]=u1.y; wih1[4*k4+2]=u1.z; wih1[4*k4+3]=u1.w;
        }
    }
    const float bias0 = (l > 0) ? (bih[l*G4 + q0] + bhh[l*G4 + q0]) : 0.f;
    const float bias1 = (l > 0) ? (bih[l*G4 + q1] + bhh[l*G4 + q1]) : 0.f;

    float c_state = 0.f;

    const float* gxb = gx0 + (size_t)b * TT * G4;
    float pf0 = 0.f, pf1 = 0.f;
    if (l == 0) { pf0 = gxb[q0]; pf1 = gxb[q1]; }

    for (int s = 0; s < TT + NL - 1; ++s) {
        const int t = s - l;
        if (0 <= t && t < TT) {
            float acc0, acc1;
            if (l == 0) {
                acc0 = pf0; acc1 = pf1;
                const int tn = t + 1;
                if (tn < TT) { pf0 = gxb[(size_t)tn * G4 + q0]; pf1 = gxb[(size_t)tn * G4 + q1]; }
            } else {
                acc0 = bias0; acc1 = bias1;
            }
            float a0a = 0.f, a0b = 0.f, a1a = 0.f, a1b = 0.f;
            if (t > 0) {
                const float4* hp = (const float4*)hbuf[l][(t - 1) & 1];
                #pragma unroll
                for (int k4 = 0; k4 < 8; ++k4) {
                    float4 v = hp[k4];
                    a0a = fmaf(whh0[4*k4+0], v.x, a0a); a0b = fmaf(whh0[4*k4+1], v.y, a0b);
                    a0a = fmaf(whh0[4*k4+2], v.z, a0a); a0b = fmaf(whh0[4*k4+3], v.w, a0b);
                    a1a = fmaf(whh1[4*k4+0], v.x, a1a); a1b = fmaf(whh1[4*k4+1], v.y, a1b);
                    a1a = fmaf(whh1[4*k4+2], v.z, a1a); a1b = fmaf(whh1[4*k4+3], v.w, a1b);
                }
            }
            if (l > 0) {
                const float4* hq = (const float4*)hbuf[l - 1][t & 1];
                #pragma unroll
                for (int k4 = 0; k4 < 8; ++k4) {
                    float4 v = hq[k4];
                    a0a = fmaf(wih0[4*k4+0], v.x, a0a); a0b = fmaf(wih0[4*k4+1], v.y, a0b);
                    a0a = fmaf(wih0[4*k4+2], v.z, a0a); a0b = fmaf(wih0[4*k4+3], v.w, a0b);
                    a1a = fmaf(wih1[4*k4+0], v.x, a1a); a1b = fmaf(wih1[4*k4+1], v.y, a1b);
                    a1a = fmaf(wih1[4*k4+2], v.z, a1a); a1b = fmaf(wih1[4*k4+3], v.w, a1b);
                }
            }
            acc0 += a0a + a0b;
            acc1 += a1a + a1b;
            gbuf[l][q0] = acc0;
            gbuf[l][q1] = acc1;
            asm volatile("s_waitcnt lgkmcnt(0)" ::: "memory");
            if (lane < HS) {
                const float ig = gbuf[l][lane];
                const float fg = gbuf[l][HS + lane];
                const float gg = gbuf[l][2*HS + lane];
                const float og = gbuf[l][3*HS + lane];
                c_state = sigm(fg) * c_state + sigm(ig) * tanh_f(gg);
                const float hv = sigm(og) * tanh_f(c_state);
                hbuf[l][t & 1][lane] = hv;
                if (l == NL - 1) h7[t][lane] = hv;
            }
        }
        __syncthreads();
    }

    float part = 0.f;
    for (int t = tid; t < TT; t += 512) {
        float st = 0.f;
        #pragma unroll
        for (int j = 0; j < HS; ++j) st = fmaf(h7[t][j], Wfc1[j], st);
        part += (st + bfc1[0]) * Wfc2[t];
    }
    #pragma unroll
    for (int off = 32; off >= 1; off >>= 1) part += __shfl_down(part, off, 64);
    if (lane == 0) red[l] = part;
    __syncthreads();
    if (tid == 0) {
        float tot = 0.f;
        #pragma unroll
        for (int w = 0; w < NL; ++w) tot += red[w];
        out[b] = tot + bfc2[0];
    }
}

// ---------------------------------------------------------------------------
extern "C" void kernel_launch(void* const* d_in, const int* in_sizes, int n_in,
                              void* d_out, int out_size, void* d_ws, size_t ws_size,
                              hipStream_t stream) {
    const float* x    = (const float*)d_in[0];
    const float* W0   = (const float*)d_in[1];
    const float* b0   = (const float*)d_in[2];
    const float* W1   = (const float*)d_in[3];
    const float* b1   = (const float*)d_in[4];
    const float* Wih0 = (const float*)d_in[5];
    const float* Wih  = (const float*)d_in[6];
    const float* Whh  = (const float*)d_in[7];
    const float* bih  = (const float*)d_in[8];
    const float* bhh  = (const float*)d_in[9];
    const float* Wfc1 = (const float*)d_in[10];
    const float* bfc1 = (const float*)d_in[11];
    const float* Wfc2 = (const float*)d_in[12];
    const float* bfc2 = (const float*)d_in[13];

    // workspace layout
    char* wsb = (char*)d_ws;
    float*          gx0 = (float*)wsb;                                   // 9,830,400 B
    unsigned short* wh  = (unsigned short*)(wsb + 9830400);              //   524,288 B
    unsigned short* wl  = (unsigned short*)(wsb + 9830400 + 524288);     //   524,288 B
    float*          prt = (float*)(wsb + 9830400 + 1048576);             // 19,660,800 B

    w0split <<<256, 256, 0, stream>>>(W0, wh, wl);
    fc_gemm1<<<dim3(MROWS / 64, KS), 256, 0, stream>>>(x, wh, wl, prt);
    fc_tail <<<MROWS / 64, 256, 0, stream>>>(prt, b0, W1, b1, Wih0, bih, bhh, gx0);
    lstm_all<<<BB, 512, 0, stream>>>(gx0, Wih, Whh, bih, bhh, Wfc1, bfc1, Wfc2, bfc2,
                                     (float*)d_out);
}